// Round 1
// baseline (350.505 us; speedup 1.0000x reference)
//
#include <hip/hip_runtime.h>
#include <cstdint>

#define BN_EPS 1e-5f

typedef unsigned int uint;

// ---------------------------------------------------------------------------
// Shapes (compile-time constants for this problem):
//   x:  (32, 256, 28, 28) f32
//   w1: (1024, 256, 3, 3) f32   conv1: 256 -> 1024, all groups share input x
//   w2: (1024, 256, 3, 3) f32   conv2: grouped x4, group g: in ch [g*256,(g+1)*256)
//   out: (32, 256, 28, 28) f32
// Bit packing: 256 channels -> 8 u32 words, bit (c%32) of word (c/32) = (v>=0)
// ---------------------------------------------------------------------------

// BN constant folding: bnA1=inv1, bnB1=bias1-mean1*inv1;
// bnA2=inv2*lambda[g], bnB2=(bias2-mean2*inv2)*lambda[g]
__global__ __launch_bounds__(256) void kPrep(
    const float* __restrict__ s1, const float* __restrict__ b1,
    const float* __restrict__ m1, const float* __restrict__ v1,
    const float* __restrict__ s2, const float* __restrict__ b2,
    const float* __restrict__ m2, const float* __restrict__ v2,
    const float* __restrict__ lam,
    float* __restrict__ bnA1, float* __restrict__ bnB1,
    float* __restrict__ bnA2, float* __restrict__ bnB2) {
  int t = blockIdx.x * 256 + threadIdx.x;
  if (t >= 1024) return;
  float inv1 = s1[t] / sqrtf(v1[t] + BN_EPS);
  bnA1[t] = inv1;
  bnB1[t] = b1[t] - m1[t] * inv1;
  float inv2 = s2[t] / sqrtf(v2[t] + BN_EPS);
  float l = lam[t >> 8];
  bnA2[t] = inv2 * l;
  bnB2[t] = (b2[t] - m2[t] * inv2) * l;
}

// Pack sign bits of x: A1p[pixel*8 + w], pixel = b*784 + y*28 + x.
// One wave handles (pixel, channel-block-of-64); ballot packs 64 bits.
__global__ __launch_bounds__(256) void kPackX(const float* __restrict__ x,
                                              uint* __restrict__ A1p) {
  int wg = blockIdx.x * 4 + (threadIdx.x >> 6);
  int lane = threadIdx.x & 63;
  int pixel = wg >> 2;
  int cb = wg & 3;
  int b = pixel / 784;
  int rem = pixel - b * 784;
  int c = cb * 64 + lane;
  float v = x[(b * 256 + c) * 784 + rem];
  unsigned long long m = __ballot(v >= 0.0f);
  if (lane == 0) {
    A1p[pixel * 8 + cb * 2]     = (uint)m;
    A1p[pixel * 8 + cb * 2 + 1] = (uint)(m >> 32);
  }
}

// Pack weight sign bits: Wp[(oc*9 + tap)*8 + w]; w layout (OC,256,3,3)
__global__ __launch_bounds__(256) void kPackW(const float* __restrict__ w,
                                              uint* __restrict__ Wp) {
  int wg = blockIdx.x * 4 + (threadIdx.x >> 6);
  int lane = threadIdx.x & 63;
  int oc = wg / 36;
  int r = wg - oc * 36;
  int tap = r >> 2;
  int cb = r & 3;
  float v = w[(oc * 256 + cb * 64 + lane) * 9 + tap];
  unsigned long long m = __ballot(v >= 0.0f);
  if (lane == 0) {
    Wp[(oc * 9 + tap) * 8 + cb * 2]     = (uint)m;
    Wp[(oc * 9 + tap) * 8 + cb * 2 + 1] = (uint)(m >> 32);
  }
}

// conv1 (+bn1+relu+binarize): block = 1 wave = 64 consecutive oc, fixed (b,y),
// loops x=0..27. Output packed bits A2p[pixel*32 + oc/32].
__global__ __launch_bounds__(64) void kConv1(
    const uint* __restrict__ A1p, const uint* __restrict__ W1p,
    const float* __restrict__ bnA1, const float* __restrict__ bnB1,
    uint* __restrict__ A2p) {
  const int lane = threadIdx.x;
  const int chunk = blockIdx.x;  // 0..15  (oc block of 64)
  const int y = blockIdx.y;      // 0..27
  const int b = blockIdx.z;      // 0..31
  const int oc = chunk * 64 + lane;

  __shared__ uint a[3][224];  // 3 rows x 28 pixels x 8 words
  for (int r = 0; r < 3; r++) {
    int ry = y + r - 1;
    if (ry < 0 || ry >= 28) continue;
    const uint* src = A1p + (b * 784 + ry * 28) * 8;
    for (int i = lane; i < 224; i += 64) a[r][i] = src[i];
  }
  __syncthreads();

  uint wr[72];
  const uint4* wsrc = (const uint4*)(W1p + oc * 72);
#pragma unroll
  for (int i = 0; i < 18; i++) {
    uint4 t = wsrc[i];
    wr[4 * i] = t.x; wr[4 * i + 1] = t.y; wr[4 * i + 2] = t.z; wr[4 * i + 3] = t.w;
  }
  const float inv = bnA1[oc], bb = bnB1[oc];
  uint* outp = A2p + (b * 784 + y * 28) * 32 + chunk * 2;

  for (int x = 0; x < 28; x++) {
    int acc = 0, nv = 0;
#pragma unroll
    for (int kh = 0; kh < 3; kh++) {
      const int ry = y + kh - 1;
      if (ry < 0 || ry >= 28) continue;  // uniform
#pragma unroll
      for (int kw = 0; kw < 3; kw++) {
        const int rx = x + kw - 1;
        if (rx < 0 || rx >= 28) continue;  // uniform
        const uint4* ap = (const uint4*)&a[kh][rx * 8];
        uint4 t0 = ap[0], t1 = ap[1];
        const uint* wp = &wr[(kh * 3 + kw) * 8];
        acc += __popc(t0.x ^ wp[0]) + __popc(t0.y ^ wp[1]) +
               __popc(t0.z ^ wp[2]) + __popc(t0.w ^ wp[3]) +
               __popc(t1.x ^ wp[4]) + __popc(t1.y ^ wp[5]) +
               __popc(t1.z ^ wp[6]) + __popc(t1.w ^ wp[7]);
        nv++;
      }
    }
    float val = (float)(nv * 256 - 2 * acc) * inv + bb;
    unsigned long long m = __ballot(val > 0.0f);
    if (lane == 0) {
      outp[x * 32]     = (uint)m;
      outp[x * 32 + 1] = (uint)(m >> 32);
    }
  }
}

// Per-(pixel,group) popcount sums of A2 (the "-popc(m)" term of conv2)
__global__ __launch_bounds__(256) void kS(const uint* __restrict__ A2p,
                                          uint* __restrict__ S) {
  int idx = blockIdx.x * 256 + threadIdx.x;
  if (idx >= 25088 * 4) return;
  int pix = idx >> 2, g = idx & 3;
  const uint* p = A2p + pix * 32 + g * 8;
  int t = 0;
#pragma unroll
  for (int w = 0; w < 8; w++) t += __popc(p[w]);
  S[idx] = (uint)t;
}

// conv2 + bn2*lambda + group-sum + identity + relu.
// Block 256 = 4 waves; lane -> c (64 channels), wave -> x-quarter (7 cols).
__global__ __launch_bounds__(256) void kConv2(
    const uint* __restrict__ A2p, const uint* __restrict__ W2p,
    const uint* __restrict__ S,
    const float* __restrict__ bnA2, const float* __restrict__ bnB2,
    const float* __restrict__ xin, float* __restrict__ out) {
  const int tid = threadIdx.x;
  const int lane = tid & 63;
  const int xq = tid >> 6;  // 0..3, handles x = xq*7 .. xq*7+6
  const int cchunk = blockIdx.x;  // 0..3
  const int y = blockIdx.y;       // 0..27
  const int b = blockIdx.z;       // 0..31
  const int c = cchunk * 64 + lane;

  __shared__ uint a[3][896];   // 3 rows x 28 px x 32 words
  __shared__ uint sp[3][112];  // 3 rows x 28 px x 4 groups
  for (int r = 0; r < 3; r++) {
    int ry = y + r - 1;
    if (ry < 0 || ry >= 28) continue;
    const uint* asrc = A2p + (b * 784 + ry * 28) * 32;
    for (int i = tid; i < 896; i += 256) a[r][i] = asrc[i];
    const uint* ssrc = S + (b * 784 + ry * 28) * 4;
    if (tid < 112) sp[r][tid] = ssrc[tid];
  }
  __syncthreads();

  float val[7];
#pragma unroll
  for (int i = 0; i < 7; i++) val[i] = 0.0f;

  for (int g = 0; g < 4; g++) {
    const int ocg = g * 256 + c;
    uint wr[72];
    const uint4* wsrc = (const uint4*)(W2p + ocg * 72);
#pragma unroll
    for (int i = 0; i < 18; i++) {
      uint4 t = wsrc[i];
      wr[4 * i] = t.x; wr[4 * i + 1] = t.y; wr[4 * i + 2] = t.z; wr[4 * i + 3] = t.w;
    }
    const float inv = bnA2[ocg], bb = bnB2[ocg];
#pragma unroll
    for (int xi = 0; xi < 7; xi++) {
      const int x = xq * 7 + xi;
      int acc = 0, sS = 0;
#pragma unroll
      for (int kh = 0; kh < 3; kh++) {
        if (y + kh - 1 < 0 || y + kh - 1 >= 28) continue;  // uniform
#pragma unroll
        for (int kw = 0; kw < 3; kw++) {
          const int rx = x + kw - 1;
          if (rx < 0 || rx >= 28) continue;  // wave-uniform
          sS += (int)sp[kh][rx * 4 + g];
          const uint4* ap = (const uint4*)&a[kh][rx * 32 + g * 8];
          uint4 t0 = ap[0], t1 = ap[1];
          const uint* wp = &wr[(kh * 3 + kw) * 8];
          acc += __popc(t0.x & wp[0]) + __popc(t0.y & wp[1]) +
                 __popc(t0.z & wp[2]) + __popc(t0.w & wp[3]) +
                 __popc(t1.x & wp[4]) + __popc(t1.y & wp[5]) +
                 __popc(t1.z & wp[6]) + __popc(t1.w & wp[7]);
        }
      }
      val[xi] += (float)(2 * acc - sS) * inv + bb;
    }
  }

  const long base = ((long)(b * 256 + c) * 28 + y) * 28;
#pragma unroll
  for (int xi = 0; xi < 7; xi++) {
    const int x = xq * 7 + xi;
    float o = val[xi] + xin[base + x];
    out[base + x] = fmaxf(o, 0.0f);
  }
}

extern "C" void kernel_launch(void* const* d_in, const int* in_sizes, int n_in,
                              void* d_out, int out_size, void* d_ws, size_t ws_size,
                              hipStream_t stream) {
  const float* x   = (const float*)d_in[0];
  const float* w1  = (const float*)d_in[1];
  const float* s1  = (const float*)d_in[2];
  const float* b1  = (const float*)d_in[3];
  const float* m1  = (const float*)d_in[4];
  const float* v1  = (const float*)d_in[5];
  const float* w2  = (const float*)d_in[6];
  const float* s2  = (const float*)d_in[7];
  const float* b2  = (const float*)d_in[8];
  const float* m2  = (const float*)d_in[9];
  const float* v2  = (const float*)d_in[10];
  const float* lam = (const float*)d_in[11];
  float* out = (float*)d_out;

  char* ws = (char*)d_ws;
  // workspace layout (bytes), all 256B aligned; total ~4.8 MB
  uint*  A1p  = (uint*)(ws + 0);          //   802816 B: 25088 px x 8 words
  uint*  W1p  = (uint*)(ws + 802816);     //   294912 B: 1024 oc x 9 taps x 8 w
  uint*  W2p  = (uint*)(ws + 1097728);    //   294912 B
  uint*  A2p  = (uint*)(ws + 1392640);    //  3211264 B: 25088 px x 32 words
  uint*  Sb   = (uint*)(ws + 4603904);    //   401408 B: 25088 px x 4 groups
  float* bnA1 = (float*)(ws + 5005312);
  float* bnB1 = (float*)(ws + 5009408);
  float* bnA2 = (float*)(ws + 5013504);
  float* bnB2 = (float*)(ws + 5017600);

  kPrep<<<4, 256, 0, stream>>>(s1, b1, m1, v1, s2, b2, m2, v2, lam,
                               bnA1, bnB1, bnA2, bnB2);
  kPackX<<<25088, 256, 0, stream>>>(x, A1p);   // 25088 px * 4 cb waves
  kPackW<<<9216, 256, 0, stream>>>(w1, W1p);   // 1024*9*4 waves
  kPackW<<<9216, 256, 0, stream>>>(w2, W2p);
  kConv1<<<dim3(16, 28, 32), 64, 0, stream>>>(A1p, W1p, bnA1, bnB1, A2p);
  kS<<<(25088 * 4 + 255) / 256, 256, 0, stream>>>(A2p, Sb);
  kConv2<<<dim3(4, 28, 32), 256, 0, stream>>>(A2p, W2p, Sb, bnA2, bnB2, x, out);
}